// Round 7
// baseline (1036.148 us; speedup 1.0000x reference)
//
#include <hip/hip_runtime.h>
#include <hip/hip_bf16.h>

#define MM 8192
#define NN 11008
#define PKW 2048   // packed int32 words per output row
#define KK 4096

#define BM 256
#define BN 256
#define BK 64
#define NT (KK / BK)   // 64 K-tiles

typedef __attribute__((ext_vector_type(4))) float f32x4;
typedef __attribute__((ext_vector_type(4))) int   i32x4;
typedef __attribute__((ext_vector_type(8))) short s16x8;
typedef __attribute__((ext_vector_type(4))) short s16x4;

typedef __attribute__((address_space(3))) unsigned char        lds_u8;
typedef const __attribute__((address_space(1))) unsigned char  glb_u8;

static __device__ __forceinline__ unsigned short f2bf(float f) {
  union { float f; unsigned int u; } v; v.f = f;
  unsigned int u = v.u;
  u += 0x7fffu + ((u >> 16) & 1u);   // RNE
  return (unsigned short)(u >> 16);
}

// ---------------- preprocessing (writes PRE-SWIZZLED: 16B group g -> g ^ (row&7)
// within each 64-element block; GEMM stages linearly via global_load_lds and
// applies the same XOR on ds_read — rule #21 both-sides) ----------------

__global__ void int4lin_cvt_x(const float* __restrict__ X, unsigned short* __restrict__ O) {
  const int n8 = (MM * KK) / 8;
  int i = blockIdx.x * blockDim.x + threadIdx.x;
  const int stride = gridDim.x * blockDim.x;
  for (; i < n8; i += stride) {
    const int row = i >> 9;            // KK/8 = 512 groups per row
    const int g   = i & 511;
    const int gs  = (g & ~7) | ((g & 7) ^ (row & 7));   // swizzled group
    const f32x4* p = (const f32x4*)(X + (size_t)i * 8);
    f32x4 a = p[0];
    f32x4 b = p[1];
    s16x8 o;
    o[0] = (short)f2bf(a[0]); o[1] = (short)f2bf(a[1]);
    o[2] = (short)f2bf(a[2]); o[3] = (short)f2bf(a[3]);
    o[4] = (short)f2bf(b[0]); o[5] = (short)f2bf(b[1]);
    o[6] = (short)f2bf(b[2]); o[7] = (short)f2bf(b[3]);
    *(s16x8*)(O + (size_t)row * KK + (size_t)gs * 8) = o;
  }
}

__global__ void int4lin_deq_w(const int* __restrict__ P, unsigned short* __restrict__ O) {
  const int n4 = (NN * PKW) / 4;     // each i: 4 words -> one 8-elem bf16 group
  int i = blockIdx.x * blockDim.x + threadIdx.x;
  const int stride = gridDim.x * blockDim.x;
  for (; i < n4; i += stride) {
    const int row = i >> 9;            // 512 groups per row
    const int g   = i & 511;
    const int gs  = (g & ~7) | ((g & 7) ^ (row & 7));
    i32x4 v = *(const i32x4*)(P + (size_t)i * 4);
    s16x8 o;
#pragma unroll
    for (int j = 0; j < 4; ++j) {
      int b = v[j];
      o[2 * j]     = (short)f2bf((float)((b & 15) - 7));
      o[2 * j + 1] = (short)f2bf((float)(((b >> 4) & 15) - 7));
    }
    *(s16x8*)(O + (size_t)row * KK + (size_t)gs * 8) = o;
  }
}

// ---------------- 256x256 GEMM, quadrant read-ahead pipeline ----------------
//
// Per tile, quadrants q0=(mlo,kk0) q1=(mlo,kk1) q2=(mhi,kk0) q3=(mhi,kk1).
// Program order issues quadrant q+1's ds_reads BEFORE quadrant q's MFMAs, so
// the compiler's auto lgkmcnt waits are counted (never drain-to-0) and the
// LDS pipe serves q+1 while the matrix pipe runs q. No setprio in the K-loop
// (suspected scheduling fence). Sync: S1 (mid-tile, stage safety) + S2
// (boundary, vmcnt(6) ring) only — ledger identical to R5:
//   tile start: stage A(t+1) late quarters; post-S1: B(t+2) + A(t+2) early.
//   At S2 of t, 6 loads issued after tile-(t+1)'s newest -> vmcnt(6).

__global__ __launch_bounds__(512, 2) void int4lin_gemm_pl(
    const unsigned short* __restrict__ Aw,   // M x K bf16, group-swizzled
    const unsigned short* __restrict__ Bw,   // N x K bf16 (q values), group-swizzled
    const float* __restrict__ scale,
    const float* __restrict__ bias,
    float* __restrict__ C)
{
  __shared__ unsigned short As[2][BM * BK];   // 2 x 32 KiB
  __shared__ unsigned short Bs[2][BN * BK];   // 2 x 32 KiB  -> 128 KiB total

  const int tid  = threadIdx.x;
  const int lane = tid & 63;
  const int wave = tid >> 6;
  const int wm = wave >> 2;          // 0..1
  const int wn = wave & 3;           // 0..3

  // T1: bijective XCD swizzle (1376 = 8*172); consecutive swz share bm (A-panel in L2)
  const int bid = blockIdx.x;
  const int swz = (bid & 7) * 172 + (bid >> 3);
  const int bm = swz / 43;
  const int bn = swz - bm * 43;
  const size_t m0 = (size_t)bm * BM;
  const size_t n0 = (size_t)bn * BN;

  const int rsel = lane & 15;
  const int gq   = lane >> 4;        // k-slot base (0..3); kk1 slot = gq+4
  const int rx7  = lane & 7;         // T2 swizzle key (== row&7 of fragment rows)

  f32x4 acc[8][4] = {};

  const int arow = wm * 128 + rsel;  // + m*16
  const int brow = wn * 64  + rsel;  // + n*16

  // LDS fragment read with T2 XOR on the 16B slot index
#define LDF(base, row, slot) \
  (*(const s16x8*)((const char*)(base) + (size_t)((row) * 128 + (((slot) ^ rx7) << 4))))

  const int srow = tid >> 3;          // 0..63
  const int scol = (tid & 7) << 3;    // bf16 col, x8

  // one 64x64 quarter = 8 KiB = 1 global_load_lds per thread
  auto stage_a_q = [&](int buf, int kt, int q) {
    __builtin_amdgcn_global_load_lds(
        (glb_u8*)(Aw + (m0 + q * 64 + srow) * KK + kt + scol),
        (lds_u8*)((char*)&As[buf][0] + q * 8192 + tid * 16), 16, 0, 0);
  };
  auto stage_b_q = [&](int buf, int kt, int q) {
    __builtin_amdgcn_global_load_lds(
        (glb_u8*)(Bw + (n0 + q * 64 + srow) * KK + kt + scol),
        (lds_u8*)((char*)&Bs[buf][0] + q * 8192 + tid * 16), 16, 0, 0);
  };

  // -------- prologue: tile0 fully (8), tile1 partially (6); vmcnt(6) --------
#pragma unroll
  for (int q = 0; q < 4; ++q) stage_b_q(0, 0, q);
  stage_a_q(0, 0, 0); stage_a_q(0, 0, 2);
  stage_a_q(0, 0, 1); stage_a_q(0, 0, 3);
#pragma unroll
  for (int q = 0; q < 4; ++q) stage_b_q(1, BK, q);
  stage_a_q(1, BK, 0); stage_a_q(1, BK, 2);
  asm volatile("s_waitcnt vmcnt(6)\n\ts_barrier" ::: "memory");

#pragma unroll 1
  for (int t = 0; t < NT; ++t) {
    const int rbuf = t & 1;
    const unsigned short* Ab = &As[rbuf][0];
    const unsigned short* Bb = &Bs[rbuf][0];
    s16x8 a0[4], a1[4], a2[4], a3[4], b0[4], b1[4];

    // q0 reads (8)
#pragma unroll
    for (int m = 0; m < 4; ++m) a0[m] = LDF(Ab, arow + m * 16, gq);
#pragma unroll
    for (int n = 0; n < 4; ++n) b0[n] = LDF(Bb, brow + n * 16, gq);
    // stage A(t+1) late quarters
    if (t + 1 < NT) {
      stage_a_q(rbuf ^ 1, (t + 1) * BK, 1);
      stage_a_q(rbuf ^ 1, (t + 1) * BK, 3);
    }
    // q1 reads (8) — issued BEFORE q0's MFMAs
#pragma unroll
    for (int m = 0; m < 4; ++m) a1[m] = LDF(Ab, arow + m * 16, gq + 4);
#pragma unroll
    for (int n = 0; n < 4; ++n) b1[n] = LDF(Bb, brow + n * 16, gq + 4);

    // MFMA q0 (compiler waits only q0's reads; q1's stay in flight)
#pragma unroll
    for (int m = 0; m < 4; ++m)
#pragma unroll
      for (int n = 0; n < 4; ++n)
        acc[m][n] = __builtin_amdgcn_mfma_f32_16x16x32_bf16(a0[m], b0[n], acc[m][n], 0, 0, 0);

    // q2 reads (4)
#pragma unroll
    for (int m = 0; m < 4; ++m) a2[m] = LDF(Ab, arow + (m + 4) * 16, gq);

    // MFMA q1
#pragma unroll
    for (int m = 0; m < 4; ++m)
#pragma unroll
      for (int n = 0; n < 4; ++n)
        acc[m][n] = __builtin_amdgcn_mfma_f32_16x16x32_bf16(a1[m], b1[n], acc[m][n], 0, 0, 0);

    // S1: all waves' B and A-early reads of this tile complete
    asm volatile("s_barrier" ::: "memory");

    // stage B(t+2) + A(t+2) early into the live buffer (rows already consumed)
    if (t + 2 < NT) {
#pragma unroll
      for (int q = 0; q < 4; ++q) stage_b_q(rbuf, (t + 2) * BK, q);
      stage_a_q(rbuf, (t + 2) * BK, 0);
      stage_a_q(rbuf, (t + 2) * BK, 2);
    }
    // q3 reads (4)
#pragma unroll
    for (int m = 0; m < 4; ++m) a3[m] = LDF(Ab, arow + (m + 4) * 16, gq + 4);

    // MFMA q2 (b0 still live)
#pragma unroll
    for (int m = 0; m < 4; ++m)
#pragma unroll
      for (int n = 0; n < 4; ++n)
        acc[m + 4][n] = __builtin_amdgcn_mfma_f32_16x16x32_bf16(a2[m], b0[n], acc[m + 4][n], 0, 0, 0);

    // MFMA q3 (b1 still live)
#pragma unroll
    for (int m = 0; m < 4; ++m)
#pragma unroll
      for (int n = 0; n < 4; ++n)
        acc[m + 4][n] = __builtin_amdgcn_mfma_f32_16x16x32_bf16(a3[m], b1[n], acc[m + 4][n], 0, 0, 0);

    // S2: tile boundary — counted wait keeps 6 loads in flight
    if (t < NT - 2)       asm volatile("s_waitcnt vmcnt(6)\n\ts_barrier" ::: "memory");
    else if (t == NT - 2) asm volatile("s_waitcnt vmcnt(0)\n\ts_barrier" ::: "memory");
    else                  asm volatile("s_barrier" ::: "memory");
  }

  // epilogue: y = acc * scale[col] + bias[col]; C/D map col=lane&15, row=gq*4+r
  const size_t crow0 = m0 + wm * 128 + (gq << 2);
  const size_t ccol0 = n0 + wn * 64 + rsel;
#pragma unroll
  for (int n = 0; n < 4; ++n) {
    const size_t gc = ccol0 + n * 16;
    const float sc = scale[gc];
    const float bi = bias[gc];
#pragma unroll
    for (int m = 0; m < 8; ++m) {
      float* cp = C + (crow0 + m * 16) * NN + gc;
#pragma unroll
      for (int r = 0; r < 4; ++r)
        cp[(size_t)r * NN] = acc[m][n][r] * sc + bi;
    }
  }
#undef LDF
}

// ---------------- GEMM, inline-conversion fallback (no workspace needed) ----------------

__global__ __launch_bounds__(256) void int4lin_gemm_inline(
    const float* __restrict__ X,
    const int* __restrict__ P,
    const float* __restrict__ scale,
    const float* __restrict__ bias,
    float* __restrict__ C)
{
  __shared__ unsigned short As[128 * BK];
  __shared__ unsigned short Bs[128 * BK];

  const int tid  = threadIdx.x;
  const int lane = tid & 63;
  const int wave = tid >> 6;
  const int m0 = blockIdx.y * 128;
  const int n0 = blockIdx.x * 128;
  const int wr = (wave >> 1) * 64;
  const int wc = (wave & 1) * 64;

  f32x4 acc[4][4] = {};

  for (int kt = 0; kt < KK; kt += BK) {
#pragma unroll
    for (int i = 0; i < 8; ++i) {
      const int idx = i * 256 + tid;
      const int row = idx >> 4;
      const int c   = (idx & 15) << 2;
      f32x4 v = *(const f32x4*)(X + (size_t)(m0 + row) * KK + kt + c);
      s16x4 o;
      o[0] = (short)f2bf(v[0]); o[1] = (short)f2bf(v[1]);
      o[2] = (short)f2bf(v[2]); o[3] = (short)f2bf(v[3]);
      *(s16x4*)(As + row * BK + (c ^ ((row & 7) << 3))) = o;
    }
#pragma unroll
    for (int i = 0; i < 4; ++i) {
      const int idx = i * 256 + tid;
      const int row = idx >> 3;
      const int c   = (idx & 7) << 3;
      i32x4 v = *(const i32x4*)(P + (size_t)(n0 + row) * PKW + ((kt + c) >> 1));
      s16x8 o;
#pragma unroll
      for (int j = 0; j < 4; ++j) {
        const int b = v[j];
        o[2 * j]     = (short)f2bf((float)((b & 15) - 7));
        o[2 * j + 1] = (short)f2bf((float)(((b >> 4) & 15) - 7));
      }
      *(s16x8*)(Bs + row * BK + (c ^ ((row & 7) << 3))) = o;
    }
    __syncthreads();
#pragma unroll
    for (int kk = 0; kk < 2; ++kk) {
      const int rsel = lane & 15;
      const int ksel = ((((lane >> 4) << 3) + kk * 32)) ^ ((lane & 7) << 3);
      s16x8 af[4], bfr[4];
#pragma unroll
      for (int m = 0; m < 4; ++m)
        af[m] = *(const s16x8*)(As + (wr + m * 16 + rsel) * BK + ksel);
#pragma unroll
      for (int n = 0; n < 4; ++n)
        bfr[n] = *(const s16x8*)(Bs + (wc + n * 16 + rsel) * BK + ksel);
#pragma unroll
      for (int m = 0; m < 4; ++m)
#pragma unroll
        for (int n = 0; n < 4; ++n)
          acc[m][n] = __builtin_amdgcn_mfma_f32_16x16x32_bf16(af[m], bfr[n], acc[m][n], 0, 0, 0);
    }
    __syncthreads();
  }

  const int crow = wr + ((lane >> 4) << 2);
  const int ccol = wc + (lane & 15);
#pragma unroll
  for (int n = 0; n < 4; ++n) {
    const int gc = n0 + ccol + n * 16;
    const float sc = scale[gc];
    const float bi = bias[gc];
#pragma unroll
    for (int m = 0; m < 4; ++m) {
      float* cp = C + (size_t)(m0 + crow + m * 16) * NN + gc;
#pragma unroll
      for (int r = 0; r < 4; ++r)
        cp[(size_t)r * NN] = acc[m][n][r] * sc + bi;
    }
  }
}

// ---------------- launch ----------------

extern "C" void kernel_launch(void* const* d_in, const int* in_sizes, int n_in,
                              void* d_out, int out_size, void* d_ws, size_t ws_size,
                              hipStream_t stream) {
  const float* x      = (const float*)d_in[0];
  const int*   packed = (const int*)d_in[1];
  const float* scale  = (const float*)d_in[2];
  const float* bias   = (const float*)d_in[3];
  float* y = (float*)d_out;

  const size_t nA = (size_t)MM * KK * sizeof(unsigned short);   // 64 MiB
  const size_t nB = (size_t)NN * KK * sizeof(unsigned short);   // ~86 MiB

  if (ws_size >= nA + nB) {
    unsigned short* xb = (unsigned short*)d_ws;
    unsigned short* wb = (unsigned short*)((char*)d_ws + nA);
    int4lin_cvt_x<<<2048, 256, 0, stream>>>(x, xb);
    int4lin_deq_w<<<2048, 256, 0, stream>>>(packed, wb);
    int4lin_gemm_pl<<<(NN / BN) * (MM / BM), 512, 0, stream>>>(xb, wb, scale, bias, y);
  } else {
    dim3 grid(NN / 128, MM / 128);
    int4lin_gemm_inline<<<grid, 256, 0, stream>>>(x, packed, scale, bias, y);
  }
}